// Round 11
// baseline (2825.052 us; speedup 1.0000x reference)
//
#include <hip/hip_runtime.h>
#include <hip/hip_bf16.h>
#include <cstddef>

// Problem constants
#define BB 8
#define LL 5
#define NN 4096
#define NANCH 64
#define NPTS 4160      // NN + NANCH
#define MM 260         // NPTS / 16
#define NFRAME 3
#define SSEQ 780       // NFRAME * MM
#define DIMC 512
#define NHEAD 8
#define DHEAD 64
#define MLPD 1024
#define OUTD 1088
#define NROWS 6240     // BB * SSEQ
#define VPITCH 784     // vT key pitch (780 padded to 16B-aligned rows)
#define WBUFSZ 2097152 // ushorts per weight buffer (qkv|proj|ff1|ff2)

typedef __attribute__((ext_vector_type(8))) short s16x8;
typedef __attribute__((ext_vector_type(4))) float fx4;
typedef unsigned short ushort_t;
typedef unsigned int uint_t;

// exact (non-contracted) squared distance, matching numpy fp32 op order
__device__ __forceinline__ float sqdist_rn(float x1, float y1, float z1,
                                           float x2, float y2, float z2) {
    float dx = __fsub_rn(x1, x2);
    float dy = __fsub_rn(y1, y2);
    float dz = __fsub_rn(z1, z2);
    return __fadd_rn(__fadd_rn(__fmul_rn(dx, dx), __fmul_rn(dy, dy)), __fmul_rn(dz, dz));
}

__device__ __forceinline__ float gelu_exact(float v) {
    return 0.5f * v * (1.0f + erff(v * 0.70710678118654752440f));
}

// round-to-nearest bf16
__device__ __forceinline__ uint_t bf16rn(float f) {
    uint_t u = __float_as_uint(f);
    return (u + 0x7FFFu + ((u >> 16) & 1u)) >> 16;
}
// split fp32 into bf16 hi + bf16 lo (residual)
__device__ __forceinline__ void split2(float f, ushort_t& h, ushort_t& l) {
    uint_t hb = bf16rn(f);
    h = (ushort_t)hb;
    float fh = __uint_as_float(hb << 16);
    l = (ushort_t)bf16rn(f - fh);
}

// ---- DPP wave64 reductions. ctrl must be an immediate -> template param.
template <int CTRL>
__device__ __forceinline__ int dpp_mov(int v) {
    return __builtin_amdgcn_update_dpp(0, v, CTRL, 0xF, 0xF, true);
}
#define DPP_STEP_F(op, v, ctrl) v = op(v, __int_as_float(dpp_mov<ctrl>(__float_as_int(v))))
__device__ __forceinline__ float wave_max_bcast(float v) {
    DPP_STEP_F(fmaxf, v, 0x111); DPP_STEP_F(fmaxf, v, 0x112);
    DPP_STEP_F(fmaxf, v, 0x114); DPP_STEP_F(fmaxf, v, 0x118);
    DPP_STEP_F(fmaxf, v, 0x142); DPP_STEP_F(fmaxf, v, 0x143);
    return __int_as_float(__builtin_amdgcn_readlane(__float_as_int(v), 63));
}
__device__ __forceinline__ float faddf(float a, float b) { return a + b; }
__device__ __forceinline__ float wave_sum_bcast(float v) {
    DPP_STEP_F(faddf, v, 0x111); DPP_STEP_F(faddf, v, 0x112);
    DPP_STEP_F(faddf, v, 0x114); DPP_STEP_F(faddf, v, 0x118);
    DPP_STEP_F(faddf, v, 0x142); DPP_STEP_F(faddf, v, 0x143);
    return __int_as_float(__builtin_amdgcn_readlane(__float_as_int(v), 63));
}
#define DPP_STEP_I(v, ctrl) { int _x = dpp_mov<ctrl>(v); v = v > _x ? v : _x; }
__device__ __forceinline__ int wave_maxi_bcast(int v) {
    DPP_STEP_I(v, 0x111); DPP_STEP_I(v, 0x112);
    DPP_STEP_I(v, 0x114); DPP_STEP_I(v, 0x118);
    DPP_STEP_I(v, 0x142); DPP_STEP_I(v, 0x143);
    return __builtin_amdgcn_readlane(v, 63);
}
// 16-entry reduce within a DPP row; result broadcast from lane 15.
__device__ __forceinline__ float row16_maxf(float v) {
    DPP_STEP_F(fmaxf, v, 0x111); DPP_STEP_F(fmaxf, v, 0x112);
    DPP_STEP_F(fmaxf, v, 0x114); DPP_STEP_F(fmaxf, v, 0x118);
    return __int_as_float(__builtin_amdgcn_readlane(__float_as_int(v), 15));
}
__device__ __forceinline__ int row16_maxi(int v) {
    DPP_STEP_I(v, 0x111); DPP_STEP_I(v, 0x112);
    DPP_STEP_I(v, 0x114); DPP_STEP_I(v, 0x118);
    return __builtin_amdgcn_readlane(v, 15);
}

// ---------------------------------------------------------------------------
// Generic weight transpose + bf16 split, one 32x32 tile per call.
// ---------------------------------------------------------------------------
__device__ __forceinline__ void wsplit_tile(
    int bid, int tid, int nthr,
    const float* __restrict__ qkvw, const float* __restrict__ projw,
    const float* __restrict__ ff1w, const float* __restrict__ ff2w,
    ushort_t* __restrict__ th, ushort_t* __restrict__ tl,
    float (*T)[33]) {
    const float* src; int K, N; size_t dst;
    if (bid < 768)       { src = qkvw;  K = 512;  N = 1536; dst = 0;       }
    else if (bid < 1024) { src = projw; K = 512;  N = 512;  dst = 786432;  bid -= 768;  }
    else if (bid < 1536) { src = ff1w;  K = 512;  N = 1024; dst = 1048576; bid -= 1024; }
    else                 { src = ff2w;  K = 1024; N = 512;  dst = 1572864; bid -= 1536; }
    int ntn = N >> 5;
    int tn = bid % ntn, tk = bid / ntn;
    int n0 = tn * 32, k0 = tk * 32;
    for (int e = tid; e < 1024; e += nthr) {
        int r = e >> 5, c = e & 31;
        T[r][c] = src[(size_t)(k0 + r) * N + n0 + c];
    }
    __syncthreads();
    for (int e = tid; e < 1024; e += nthr) {
        int r = e >> 5, c = e & 31;
        ushort_t h, l;
        split2(T[c][r], h, l);
        th[dst + (size_t)(n0 + r) * K + k0 + c] = h;
        tl[dst + (size_t)(n0 + r) * K + k0 + c] = l;
    }
}

// ---------------------------------------------------------------------------
__global__ __launch_bounds__(256) void build_pts_kernel(const float* __restrict__ points,
                                                        float* __restrict__ pts) {
    int i = blockIdx.x * 256 + threadIdx.x;   // over B*L*NPTS = 166400
    if (i >= BB * LL * NPTS) return;
    int n = i % NPTS;
    int bl = i / NPTS;
    if (n < NN) {
        const float* src = points + ((size_t)bl * NN + n) * 3;
        pts[(size_t)i * 3 + 0] = src[0];
        pts[(size_t)i * 3 + 1] = src[1];
        pts[(size_t)i * 3 + 2] = src[2];
    } else {
        int j = n - NN;
        int ix = j >> 4, iy = (j >> 2) & 3, iz = j & 3;
        pts[(size_t)i * 3 + 0] = -1.5f + (float)ix;
        pts[(size_t)i * 3 + 1] = -1.5f + (float)iy;
        pts[(size_t)i * 3 + 2] = -1.5f + (float)iz;
    }
}

// ---------------------------------------------------------------------------
// FPS (blocks 0..23, 1024 thr, 16 waves) + layer-0 wsplit (blocks 24..2071).
// ---------------------------------------------------------------------------
__global__ __launch_bounds__(1024) void fps_ws_kernel(
    const float* __restrict__ pts, float* __restrict__ axyz,
    const float* __restrict__ qkvw, const float* __restrict__ projw,
    const float* __restrict__ ff1w, const float* __restrict__ ff2w,
    ushort_t* __restrict__ th, ushort_t* __restrict__ tl) {
    __shared__ __align__(16) char smem[50432];
    int bid = blockIdx.x;
    int tid = threadIdx.x;
    if (bid >= 24) {
        wsplit_tile(bid - 24, tid, 1024, qkvw, projw, ff1w, ff2w, th, tl,
                    (float(*)[33])smem);
        return;
    }
    float* sx = (float*)smem;
    float* sy = sx + NPTS;
    float* sz = sy + NPTS;
    float* redv = sz + NPTS;          // [2][16]
    int* redi = (int*)(redv + 32);    // [2][16]

    int b = bid / 3, f = bid % 3;
    const float* P = pts + (size_t)(b * LL + 2 * f) * NPTS * 3;
    int lane = tid & 63, wid = tid >> 6;
    const int PPT = 5;                // ceil(4160/1024)
    float px[PPT], py[PPT], pz[PPT], dist[PPT];
#pragma unroll
    for (int j = 0; j < PPT; j++) {
        int n = tid + 1024 * j;
        if (n < NPTS) {
            float gx = P[(size_t)n * 3 + 0];
            float gy = P[(size_t)n * 3 + 1];
            float gz = P[(size_t)n * 3 + 2];
            px[j] = gx; py[j] = gy; pz[j] = gz;
            sx[n] = gx; sy[n] = gy; sz[n] = gz;
            dist[j] = 1e10f;
        } else {
            px[j] = 0.f; py[j] = 0.f; pz[j] = 0.f;
            dist[j] = -1.0f;          // never selected
        }
    }
    __syncthreads();
    float ax = sx[0], ay = sy[0], az = sz[0];
    float* out = axyz + (size_t)bid * MM * 3;
    for (int m = 0; m < MM; m++) {
        if (tid == 0) { out[m * 3 + 0] = ax; out[m * 3 + 1] = ay; out[m * 3 + 2] = az; }
        float bestv = -1.0f;
        int bestn = NPTS;
#pragma unroll
        for (int j = 0; j < PPT; j++) {
            int n = tid + 1024 * j;
            if (n < NPTS) {
                float d = sqdist_rn(px[j], py[j], pz[j], ax, ay, az);
                float dj = fminf(dist[j], d);
                dist[j] = dj;
                if (dj > bestv) { bestv = dj; bestn = n; }  // ascending n: keeps first
            }
        }
        float wm = wave_max_bcast(bestv);
        int wn = 0x7FFFFFFF - wave_maxi_bcast(bestv == wm ? (0x7FFFFFFF - bestn) : 0);
        int par = (m & 1) * 16;
        if (lane == 0) { redv[par + wid] = wm; redi[par + wid] = wn; }
        __syncthreads();
        float cv = redv[par + (lane & 15)];
        int ci = redi[par + (lane & 15)];
        float bv = row16_maxf(cv);
        int bn = 0x7FFFFFFF - row16_maxi(cv == bv ? (0x7FFFFFFF - ci) : 0);
        ax = sx[bn]; ay = sy[bn]; az = sz[bn];
    }
}

// ---------------------------------------------------------------------------
// Ball query + grouped conv + max over k + max over window + pos embedding.
// ---------------------------------------------------------------------------
__global__ __launch_bounds__(64) void group_conv_kernel(
    const float* __restrict__ pts, const float* __restrict__ axyz,
    const float* __restrict__ conv_d_w, const float* __restrict__ conv_f_w,
    const float* __restrict__ pos_w, const float* __restrict__ pos_b,
    float* __restrict__ x) {
    int gid = blockIdx.x;                 // b*780 + f*260 + m
    int b = gid / SSEQ;
    int rem = gid % SSEQ;
    int f = rem / MM;
    int lane = threadIdx.x;
    const float* A = axyz + (size_t)gid * 3;
    float ax = A[0], ay = A[1], az = A[2];

    float cf0[8], cf1[8], cf2[8], cd0[8], cd1[8], cd2[8], cd3[8], fmx[8];
#pragma unroll
    for (int c = 0; c < 8; c++) {
        int d = lane + 64 * c;
        cf0[c] = conv_f_w[d * 3 + 0];
        cf1[c] = conv_f_w[d * 3 + 1];
        cf2[c] = conv_f_w[d * 3 + 2];
        cd0[c] = conv_d_w[d * 4 + 0];
        cd1[c] = conv_d_w[d * 4 + 1];
        cd2[c] = conv_d_w[d * 4 + 2];
        cd3[c] = conv_d_w[d * 4 + 3];
        fmx[c] = -INFINITY;
    }
    __shared__ int nbr[32];
    __shared__ float gxs[32], gys[32], gzs[32];
    const float R2 = 0.49000000953674316f;

    for (int wi = 0; wi < 3; wi++) {
        int l = 2 * f + wi - 1;
        l = l < 0 ? 0 : (l > 4 ? 4 : l);
        const float* P = pts + (size_t)(b * LL + l) * NPTS * 3;
        int cnt = 0;
        for (int base = 0; base < NPTS && cnt < 32; base += 64) {
            int n = base + lane;
            float d2 = sqdist_rn(P[(size_t)n * 3], P[(size_t)n * 3 + 1], P[(size_t)n * 3 + 2],
                                 ax, ay, az);
            bool hit = d2 < R2;
            unsigned long long mk = __ballot(hit);
            int rank = (int)__popcll(mk & (((unsigned long long)1 << lane) - 1ull));
            if (hit && (cnt + rank) < 32) nbr[cnt + rank] = n;
            cnt += (int)__popcll(mk);
        }
        __syncthreads();
        int eff = cnt < 32 ? cnt : 32;
        if (lane < 32) {
            int idx = (eff == 0) ? 0 : (lane < eff ? nbr[lane] : nbr[0]);
            gxs[lane] = P[(size_t)idx * 3 + 0];
            gys[lane] = P[(size_t)idx * 3 + 1];
            gzs[lane] = P[(size_t)idx * 3 + 2];
        }
        __syncthreads();
        float tf = (float)(wi - 1);
        for (int k = 0; k < 32; k++) {
            float gx = gxs[k], gy = gys[k], gz = gzs[k];
            float dx = gx - ax, dy = gy - ay, dz = gz - az;
#pragma unroll
            for (int c = 0; c < 8; c++) {
                float v = gx * cf0[c] + gy * cf1[c] + gz * cf2[c] +
                          dx * cd0[c] + dy * cd1[c] + dz * cd2[c] + tf * cd3[c];
                fmx[c] = fmaxf(fmx[c], v);
            }
        }
        __syncthreads();
    }
    float tcol = (float)(f + 1);
#pragma unroll
    for (int c = 0; c < 8; c++) {
        int d = lane + 64 * c;
        float pos = ax * pos_w[d * 4 + 0] + ay * pos_w[d * 4 + 1] +
                    az * pos_w[d * 4 + 2] + tcol * pos_w[d * 4 + 3] + pos_b[d];
        x[(size_t)gid * DIMC + d] = fmx[c] + pos;
    }
}

// ---------------------------------------------------------------------------
// LayerNorm over last dim 512; output written as bf16 hi/lo split (GEMM A).
// ---------------------------------------------------------------------------
__global__ __launch_bounds__(64) void ln_kernel(const float* __restrict__ x,
                                                const float* __restrict__ g,
                                                const float* __restrict__ b,
                                                ushort_t* __restrict__ yh,
                                                ushort_t* __restrict__ yl) {
    int r = blockIdx.x;
    int lane = threadIdx.x;
    const float* xr = x + (size_t)r * DIMC;
    float4 v0 = *(const float4*)(xr + lane * 8);
    float4 v1 = *(const float4*)(xr + lane * 8 + 4);
    float s = v0.x + v0.y + v0.z + v0.w + v1.x + v1.y + v1.z + v1.w;
    s = wave_sum_bcast(s);
    float mean = s * (1.0f / 512.0f);
    float dv[8];
    dv[0] = v0.x - mean; dv[1] = v0.y - mean; dv[2] = v0.z - mean; dv[3] = v0.w - mean;
    dv[4] = v1.x - mean; dv[5] = v1.y - mean; dv[6] = v1.z - mean; dv[7] = v1.w - mean;
    float sq = 0.f;
#pragma unroll
    for (int c = 0; c < 8; c++) sq += dv[c] * dv[c];
    sq = wave_sum_bcast(sq);
    float var = sq * (1.0f / 512.0f);
    float inv = 1.0f / sqrtf(var + 1e-5f);
    int d = lane * 8;
    ushort_t hs[8], ls[8];
#pragma unroll
    for (int c = 0; c < 8; c++) {
        float v = dv[c] * inv * g[d + c] + b[d + c];
        split2(v, hs[c], ls[c]);
    }
    uint4 hv, lv;
    hv.x = hs[0] | ((uint_t)hs[1] << 16); hv.y = hs[2] | ((uint_t)hs[3] << 16);
    hv.z = hs[4] | ((uint_t)hs[5] << 16); hv.w = hs[6] | ((uint_t)hs[7] << 16);
    lv.x = ls[0] | ((uint_t)ls[1] << 16); lv.y = ls[2] | ((uint_t)ls[3] << 16);
    lv.z = ls[4] | ((uint_t)ls[5] << 16); lv.w = ls[6] | ((uint_t)ls[7] << 16);
    *(uint4*)(yh + (size_t)r * DIMC + d) = hv;
    *(uint4*)(yl + (size_t)r * DIMC + d) = lv;
}

// ---------------------------------------------------------------------------
// bf16x3 MFMA GEMM (fp32 emulation): C = A @ W, NO LDS / NO BARRIERS.
// A row-major [M][K] hi/lo; W pre-transposed [N][K] hi/lo. Each lane's MFMA
// fragment is a contiguous 16 B global chunk (row=base+l15, k=k0+quad*8) ->
// per-lane global_load_dwordx4 directly into fragment registers. The 2x
// cross-wave fragment duplication hits L1/L2 (weights resident in L2).
// EPI: 0 = fp32 C; 2 = bias+gelu -> split (Ch,Cl); 3 = bias+R -> C;
//      5 = qkv: Q/K cols -> split (Ch,Cl) stride 1024; V cols -> transposed
//          vT[(b*8+h)*64+d][key] split (Vh,Vl), key pitch VPITCH.
// ---------------------------------------------------------------------------
template <int BN, int EPI>
__global__ __launch_bounds__(256) void gemm_mfma(
    const ushort_t* __restrict__ Ahg, const ushort_t* __restrict__ Alg,
    const ushort_t* __restrict__ Bhg, const ushort_t* __restrict__ Blg,
    const float* __restrict__ bias, const float* __restrict__ R,
    float* __restrict__ C, ushort_t* __restrict__ Ch, ushort_t* __restrict__ Cl,
    ushort_t* __restrict__ Vh, ushort_t* __restrict__ Vl,
    int M, int N, int K) {
    const int WN = BN / 2, NT = WN / 16;
    int tid = threadIdx.x;
    int lane = tid & 63, w = tid >> 6;
    int wm = w & 1, wn = w >> 1;
    int quad = lane >> 4, l15 = lane & 15;
    int m0 = blockIdx.y * 128, n0 = blockIdx.x * BN;

    // per-lane fragment source rows (clamped for the M tail)
    const ushort_t* apH[4];
    const ushort_t* apL[4];
#pragma unroll
    for (int mi = 0; mi < 4; mi++) {
        int row = m0 + 64 * wm + 16 * mi + l15;
        if (row >= M) row = M - 1;
        apH[mi] = Ahg + (size_t)row * K + quad * 8;
        apL[mi] = Alg + (size_t)row * K + quad * 8;
    }
    const ushort_t* bpH[NT];
    const ushort_t* bpL[NT];
#pragma unroll
    for (int nj = 0; nj < NT; nj++) {
        int row = n0 + WN * wn + 16 * nj + l15;
        bpH[nj] = Bhg + (size_t)row * K + quad * 8;
        bpL[nj] = Blg + (size_t)row * K + quad * 8;
    }

    fx4 acc[4][NT];
#pragma unroll
    for (int mi = 0; mi < 4; mi++)
#pragma unroll
        for (int nj = 0; nj < NT; nj++) acc[mi][nj] = (fx4){0.f, 0.f, 0.f, 0.f};

#pragma unroll 2
    for (int k0 = 0; k0 < K; k0 += 32) {
        s16x8 af[4][2], bf[NT][2];
#pragma unroll
        for (int mi = 0; mi < 4; mi++) {
            af[mi][0] = *(const s16x8*)(apH[mi] + k0);
            af[mi][1] = *(const s16x8*)(apL[mi] + k0);
        }
#pragma unroll
        for (int nj = 0; nj < NT; nj++) {
            bf[nj][0] = *(const s16x8*)(bpH[nj] + k0);
            bf[nj][1] = *(const s16x8*)(bpL[nj] + k0);
        }
#pragma unroll
        for (int mi = 0; mi < 4; mi++)
#pragma unroll
            for (int nj = 0; nj < NT; nj++) {
                acc[mi][nj] = __builtin_amdgcn_mfma_f32_16x16x32_bf16(af[mi][0], bf[nj][0], acc[mi][nj], 0, 0, 0);
                acc[mi][nj] = __builtin_amdgcn_mfma_f32_16x16x32_bf16(af[mi][0], bf[nj][1], acc[mi][nj], 0, 0, 0);
                acc[mi][nj] = __builtin_amdgcn_mfma_f32_16x16x32_bf16(af[mi][1], bf[nj][0], acc[mi][nj], 0, 0, 0);
            }
    }
#pragma unroll
    for (int mi = 0; mi < 4; mi++) {
#pragma unroll
        for (int r = 0; r < 4; r++) {
            int row = m0 + 64 * wm + 16 * mi + quad * 4 + r;
            if (row < M) {
#pragma unroll
                for (int nj = 0; nj < NT; nj++) {
                    int col = n0 + WN * wn + 16 * nj + l15;
                    float v = acc[mi][nj][r];
                    if (EPI == 0) {
                        C[(size_t)row * N + col] = v;
                    } else if (EPI == 3) {
                        C[(size_t)row * N + col] = v + bias[col] + R[(size_t)row * N + col];
                    } else if (EPI == 2) {
                        float gv = gelu_exact(v + bias[col]);
                        ushort_t h, l;
                        split2(gv, h, l);
                        Ch[(size_t)row * N + col] = h;
                        Cl[(size_t)row * N + col] = l;
                    } else if (EPI == 5) {
                        ushort_t h, l;
                        split2(v, h, l);
                        if (col < 1024) {
                            Ch[(size_t)row * 1024 + col] = h;
                            Cl[(size_t)row * 1024 + col] = l;
                        } else {
                            int bb = row / SSEQ, key = row % SSEQ;
                            int hh = (col - 1024) >> 6, dd = (col - 1024) & 63;
                            size_t vo = ((size_t)((bb * 8 + hh) * 64 + dd)) * VPITCH + key;
                            Vh[vo] = h;
                            Vl[vo] = l;
                        }
                    }
                }
            }
        }
    }
}

// ---------------------------------------------------------------------------
// MFMA flash attention (blocks x<13) + next-layer wsplit (blocks x>=13).
// ---------------------------------------------------------------------------
#define AP 72   // ushort pitch

__global__ __launch_bounds__(256, 2) void attn_mfma_kernel(
    const ushort_t* __restrict__ qkh, const ushort_t* __restrict__ qkl,
    const ushort_t* __restrict__ vth, const ushort_t* __restrict__ vtl,
    ushort_t* __restrict__ oh, ushort_t* __restrict__ ol,
    const float* __restrict__ nqkvw, const float* __restrict__ nprojw,
    const float* __restrict__ nff1w, const float* __restrict__ nff2w,
    ushort_t* __restrict__ nth, ushort_t* __restrict__ ntl) {
    __shared__ __align__(16) char smem[73728];
    if (blockIdx.x >= 13) {
        int widx = (blockIdx.x - 13) * 64 + blockIdx.y * 8 + blockIdx.z;
        wsplit_tile(widx, threadIdx.x, 256, nqkvw, nprojw, nff1w, nff2w,
                    nth, ntl, (float(*)[33])smem);
        return;
    }
    ushort_t* Qh  = (ushort_t*)smem;
    ushort_t* Ql  = Qh + 64 * AP;
    ushort_t* Kh  = Ql + 64 * AP;
    ushort_t* Kl  = Kh + 64 * AP;
    ushort_t* Vth = Kl + 64 * AP;
    ushort_t* Vtl = Vth + 64 * AP;
    ushort_t* Ph  = Vtl + 64 * AP;
    ushort_t* Pl  = Ph + 64 * AP;

    int qt = blockIdx.x, h = blockIdx.y, b = blockIdx.z;
    int tid = threadIdx.x;
    int lane = tid & 63, w = tid >> 6;
    int quad = lane >> 4, l15 = lane & 15;
    int bh = b * 8 + h;

    int q0 = qt * 64;
    int nq = SSEQ - q0; if (nq > 64) nq = 64;

    // stage Q (hi/lo), rows clamped
#pragma unroll
    for (int i = 0; i < 2; i++) {
        int t = tid + 256 * i;
        int row = t >> 3, c = (t & 7) * 8;
        int gq = q0 + (row < nq ? row : nq - 1);
        size_t go = (size_t)(b * SSEQ + gq) * 1024 + h * 64 + c;
        *(uint4*)&Qh[row * AP + c] = *(const uint4*)(qkh + go);
        *(uint4*)&Ql[row * AP + c] = *(const uint4*)(qkl + go);
    }

    fx4 accO[4];
#pragma unroll
    for (int dj = 0; dj < 4; dj++) accO[dj] = (fx4){0.f, 0.f, 0.f, 0.f};
    fx4 accL = (fx4){0.f, 0.f, 0.f, 0.f};

    s16x8 ones;
#pragma unroll
    for (int j = 0; j < 8; j++) ones[j] = (short)16256;   // bf16 1.0

    for (int kt = 0; kt < 13; kt++) {
        int k0 = kt * 64;
        int nk = SSEQ - k0; if (nk > 64) nk = 64;
        __syncthreads();   // prior QK/PV reads done before overwrite
#pragma unroll
        for (int i = 0; i < 2; i++) {
            int t = tid + 256 * i;
            int row = t >> 3, c = (t & 7) * 8;
            int gk = k0 + (row < nk ? row : nk - 1);
            size_t go = (size_t)(b * SSEQ + gk) * 1024 + h * 64 + c;
            *(uint4*)&Kh[row * AP + c] = *(const uint4*)(qkh + go + 512);
            *(uint4*)&Kl[row * AP + c] = *(const uint4*)(qkl + go + 512);
            size_t vo = ((size_t)(bh * 64 + row)) * VPITCH + k0 + c;
            *(uint4*)&Vth[row * AP + c] = *(const uint4*)(vth + vo);
            *(uint4*)&Vtl[row * AP + c] = *(const uint4*)(vtl + vo);
        }
        __syncthreads();

        // S = Q K^T (x3): wave's 16 q rows x 64 keys
        fx4 accS[4];
#pragma unroll
        for (int nj = 0; nj < 4; nj++) accS[nj] = (fx4){0.f, 0.f, 0.f, 0.f};
#pragma unroll
        for (int ks = 0; ks < 2; ks++) {
            s16x8 aH = *(const s16x8*)&Qh[(16 * w + l15) * AP + 32 * ks + quad * 8];
            s16x8 aL = *(const s16x8*)&Ql[(16 * w + l15) * AP + 32 * ks + quad * 8];
#pragma unroll
            for (int nj = 0; nj < 4; nj++) {
                s16x8 bH = *(const s16x8*)&Kh[(16 * nj + l15) * AP + 32 * ks + quad * 8];
                s16x8 bL = *(const s16x8*)&Kl[(16 * nj + l15) * AP + 32 * ks + quad * 8];
                accS[nj] = __builtin_amdgcn_mfma_f32_16x16x32_bf16(aH, bH, accS[nj], 0, 0, 0);
                accS[nj] = __builtin_amdgcn_mfma_f32_16x16x32_bf16(aH, bL, accS[nj], 0, 0, 0);
                accS[nj] = __builtin_amdgcn_mfma_f32_16x16x32_bf16(aL, bH, accS[nj], 0, 0, 0);
            }
        }
        // P = exp(S * scale), split hi/lo, write to wave-local LDS region
#pragma unroll
        for (int nj = 0; nj < 4; nj++) {
            int key = 16 * nj + l15;
            bool valid = key < nk;
#pragma unroll
            for (int r = 0; r < 4; r++) {
                float s = accS[nj][r] * 0.125f;
                float p = valid ? __expf(s) : 0.f;
                ushort_t hh, ll;
                split2(p, hh, ll);
                int qrow = 16 * w + quad * 4 + r;
                Ph[qrow * AP + key] = hh;
                Pl[qrow * AP + key] = ll;
            }
        }
        // PV (x3) + l-sum (ones-B); wave-local, in-order DS => no barrier
#pragma unroll
        for (int ks = 0; ks < 2; ks++) {
            s16x8 aPh = *(const s16x8*)&Ph[(16 * w + l15) * AP + 32 * ks + quad * 8];
            s16x8 aPl = *(const s16x8*)&Pl[(16 * w + l15) * AP + 32 * ks + quad * 8];
            accL = __builtin_amdgcn_mfma_f32_16x16x32_bf16(aPh, ones, accL, 0, 0, 0);
            accL = __builtin_amdgcn_mfma_f32_16x16x32_bf16(aPl, ones, accL, 0, 0, 0);
#pragma unroll
            for (int dj = 0; dj < 4; dj++) {
                s16x8 bVh = *(const s16x8*)&Vth[(16 * dj + l15) * AP + 32 * ks + quad * 8];
                s16x8 bVl = *(const s16x8*)&Vtl[(16 * dj + l15) * AP + 32 * ks + quad * 8];
                accO[dj] = __builtin_amdgcn_mfma_f32_16x16x32_bf16(aPh, bVh, accO[dj], 0, 0, 0);
                accO[dj] = __builtin_amdgcn_mfma_f32_16x16x32_bf16(aPh, bVl, accO[dj], 0, 0, 0);
                accO[dj] = __builtin_amdgcn_mfma_f32_16x16x32_bf16(aPl, bVh, accO[dj], 0, 0, 0);
            }
        }
    }
    // store O / l ; rows of accL align with rows of accO (C-layout)
#pragma unroll
    for (int r = 0; r < 4; r++) {
        int lq = 16 * w + quad * 4 + r;
        if (lq < nq) {
            float inv = 1.0f / accL[r];
            size_t base = (size_t)(b * SSEQ + q0 + lq) * DIMC + h * 64 + l15;
#pragma unroll
            for (int dj = 0; dj < 4; dj++) {
                ushort_t hh, ll;
                split2(accO[dj][r] * inv, hh, ll);
                oh[base + 16 * dj] = hh;
                ol[base + 16 * dj] = ll;
            }
        }
    }
}

// ---------------------------------------------------------------------------
// Head: two-stage max-pool + LN, then parallel head GEMVs (fp32).
// ---------------------------------------------------------------------------
__global__ __launch_bounds__(512) void pool_max_kernel(const float* __restrict__ x,
                                                       float* __restrict__ partial) {
    int c = blockIdx.x;        // 0..12 (chunks of 60 rows)
    int bb = blockIdx.y;
    int d = threadIdx.x;
    const float* xb = x + ((size_t)(bb * SSEQ + c * 60)) * DIMC + d;
    float m = -INFINITY;
#pragma unroll 4
    for (int s = 0; s < 60; s++) m = fmaxf(m, xb[(size_t)s * DIMC]);
    partial[((size_t)bb * 13 + c) * DIMC + d] = m;
}

__global__ __launch_bounds__(512) void pool_ln_kernel(const float* __restrict__ partial,
                                                      const float* __restrict__ g,
                                                      const float* __restrict__ b,
                                                      float* __restrict__ out) {
    int bb = blockIdx.x;
    int d = threadIdx.x;
    const float* pb = partial + (size_t)bb * 13 * DIMC + d;
    float m = -INFINITY;
#pragma unroll
    for (int c = 0; c < 13; c++) m = fmaxf(m, pb[(size_t)c * DIMC]);
    __shared__ float col[512];
    __shared__ float red[512];
    col[d] = m;
    red[d] = m;
    __syncthreads();
    for (int s = 256; s > 0; s >>= 1) {
        if (d < s) red[d] += red[d + s];
        __syncthreads();
    }
    float mean = red[0] * (1.0f / 512.0f);
    __syncthreads();
    float dv = col[d] - mean;
    red[d] = dv * dv;
    __syncthreads();
    for (int s = 256; s > 0; s >>= 1) {
        if (d < s) red[d] += red[d + s];
        __syncthreads();
    }
    float var = red[0] * (1.0f / 512.0f);
    float inv = 1.0f / sqrtf(var + 1e-5f);
    out[(size_t)bb * DIMC + d] = dv * inv * g[d] + b[d];
}

__global__ __launch_bounds__(256) void head1_kernel(const float* __restrict__ in,
                                                    const float* __restrict__ W,
                                                    const float* __restrict__ bias,
                                                    float* __restrict__ out) {
    int g = blockIdx.x, bb = blockIdx.y;
    int tid = threadIdx.x;
    int c = tid & 63, ks = tid >> 6;
    int col = g * 64 + c;
    __shared__ float xr[512];
    xr[tid] = in[(size_t)bb * 512 + tid];
    xr[tid + 256] = in[(size_t)bb * 512 + tid + 256];
    __syncthreads();
    float acc = 0.f;
    const float* Wc = W + col;
    for (int k = ks * 128; k < ks * 128 + 128; k++)
        acc += xr[k] * Wc[(size_t)k * MLPD];
    __shared__ float red[256];
    red[tid] = acc;
    __syncthreads();
    if (ks == 0) {
        float v = red[c] + red[c + 64] + red[c + 128] + red[c + 192] + bias[col];
        out[(size_t)bb * MLPD + col] = gelu_exact(v);
    }
}

__global__ __launch_bounds__(256) void head2_kernel(const float* __restrict__ in,
                                                    const float* __restrict__ W,
                                                    const float* __restrict__ bias,
                                                    float* __restrict__ out) {
    int g = blockIdx.x, bb = blockIdx.y;
    int tid = threadIdx.x;
    int c = tid & 63, ks = tid >> 6;
    int col = g * 64 + c;
    __shared__ float xr[1024];
    xr[tid] = in[(size_t)bb * 1024 + tid];
    xr[tid + 256] = in[(size_t)bb * 1024 + tid + 256];
    xr[tid + 512] = in[(size_t)bb * 1024 + tid + 512];
    xr[tid + 768] = in[(size_t)bb * 1024 + tid + 768];
    __syncthreads();
    float acc = 0.f;
    const float* Wc = W + col;
    for (int k = ks * 256; k < ks * 256 + 256; k++)
        acc += xr[k] * Wc[(size_t)k * OUTD];
    __shared__ float red[256];
    red[tid] = acc;
    __syncthreads();
    if (ks == 0) {
        out[(size_t)bb * OUTD + col] = red[c] + red[c + 64] + red[c + 128] + red[c + 192] + bias[col];
    }
}

__global__ __launch_bounds__(64) void smax_anchor_kernel(const float* __restrict__ h2,
                                                         float* __restrict__ out) {
    int bb = blockIdx.x / 17;
    int gcol = blockIdx.x % 17;
    int j = threadIdx.x;
    float v = h2[(size_t)bb * OUTD + gcol * 64 + j];
    float mx = wave_max_bcast(v);
    float p = expf(v - mx);
    float sum = wave_sum_bcast(p);
    int ix = j >> 4, iy = (j >> 2) & 3, iz = j & 3;
    float sx = wave_sum_bcast(p * (-1.5f + (float)ix));
    float sy = wave_sum_bcast(p * (-1.5f + (float)iy));
    float sz = wave_sum_bcast(p * (-1.5f + (float)iz));
    if (j == 0) {
        float* o = out + ((size_t)bb * 17 + gcol) * 3;
        o[0] = sx / sum;
        o[1] = sy / sum;
        o[2] = sz / sum;
    }
}

// ---------------------------------------------------------------------------
extern "C" void kernel_launch(void* const* d_in, const int* in_sizes, int n_in,
                              void* d_out, int out_size, void* d_ws, size_t ws_size,
                              hipStream_t stream) {
    const float* points     = (const float*)d_in[0];
    const float* conv_d_w   = (const float*)d_in[1];
    const float* conv_f_w   = (const float*)d_in[2];
    const float* pos_w      = (const float*)d_in[3];
    const float* pos_b      = (const float*)d_in[4];
    const float* ln1_g      = (const float*)d_in[5];
    const float* ln1_b      = (const float*)d_in[6];
    const float* qkv_w      = (const float*)d_in[7];
    const float* attn_out_w = (const float*)d_in[8];
    const float* attn_out_b = (const float*)d_in[9];
    const float* ln2_g      = (const float*)d_in[10];
    const float* ln2_b      = (const float*)d_in[11];
    const float* ff1_w      = (const float*)d_in[12];
    const float* ff1_b      = (const float*)d_in[13];
    const float* ff2_w      = (const float*)d_in[14];
    const float* ff2_b      = (const float*)d_in[15];
    const float* head_ln_g  = (const float*)d_in[16];
    const float* head_ln_b  = (const float*)d_in[17];
    const float* head1_w    = (const float*)d_in[18];
    const float* head1_b    = (const float*)d_in[19];
    const float* head2_w    = (const float*)d_in[20];
    const float* head2_b    = (const float*)d_in[21];

    // fp32 region
    float* ws = (float*)d_ws;
    float* pts    = ws;                    //   499,200 f
    float* axyz   = pts + 499200;          //    18,720 f
    float* xbuf   = axyz + 18720;          // 3,194,880 f
    float* qkvreg = xbuf + 3194880;        // 9,601,024 f (qk + vT, hi/lo)
    float* pooled = qkvreg + 9601024;      //     4,096 f
    float* h1     = pooled + 4096;         //     8,192 f
    float* h2     = h1 + 8192;             //     8,704 f
    float* fend   = h2 + 8704;
    // qk (stride 1024) + vT hi/lo inside qkvreg
    ushort_t* qkh = (ushort_t*)qkvreg;             // 6,389,760 us
    ushort_t* qkl = qkh + 6389760;                 // 6,389,760 us
    ushort_t* vth = qkl + 6389760;                 // 3,211,264 us (8*8*64*784)
    ushort_t* vtl = vth + 3211264;                 // 3,211,264 us
    // bf16 hi/lo region (ushort)
    ushort_t* us   = (ushort_t*)fend;
    ushort_t* xnh  = us;                   // 3,194,880 us
    ushort_t* xnl  = xnh + 3194880;
    ushort_t* atth = xnl + 3194880;
    ushort_t* attl = atth + 3194880;
    ushort_t* ffhh = attl + 3194880;       // 6,389,760 us
    ushort_t* ffhl = ffhh + 6389760;
    ushort_t* wbh  = ffhl + 6389760;       // 2 x WBUFSZ (ping-pong weights, hi)
    ushort_t* wbl  = wbh + 2 * WBUFSZ;     // 2 x WBUFSZ (lo)
    float* ppart = qkvreg;                 // alias: qkv dead after last layer

    build_pts_kernel<<<650, 256, 0, stream>>>(points, pts);
    // fps + layer-0 wsplit fused (blocks 24..2071 do wsplit into buffer 0)
    fps_ws_kernel<<<24 + 2048, 1024, 0, stream>>>(
        pts, axyz, qkv_w, attn_out_w, ff1_w, ff2_w, wbh, wbl);
    group_conv_kernel<<<NROWS, 64, 0, stream>>>(pts, axyz, conv_d_w, conv_f_w,
                                                pos_w, pos_b, xbuf);
    const int MB = (NROWS + 127) / 128;    // 49 row-blocks
    for (int l = 0; l < 5; l++) {
        ushort_t* wth = wbh + (size_t)(l & 1) * WBUFSZ;
        ushort_t* wtl = wbl + (size_t)(l & 1) * WBUFSZ;
        ushort_t* nth = wbh + (size_t)((l + 1) & 1) * WBUFSZ;
        ushort_t* ntl = wbl + (size_t)((l + 1) & 1) * WBUFSZ;
        int ln2off = l * 512;
        ln_kernel<<<NROWS, 64, 0, stream>>>(xbuf, ln1_g + ln2off, ln1_b + ln2off, xnh, xnl);
        gemm_mfma<128, 5><<<dim3(1536 / 128, MB), 256, 0, stream>>>(
            xnh, xnl, wth, wtl, nullptr, nullptr, nullptr, qkh, qkl, vth, vtl,
            NROWS, 1536, 512);
        // attn + next-layer wsplit fused (x >= 13 blocks fill buffer (l+1)&1)
        int lnx = l + 1;
        attn_mfma_kernel<<<dim3(l < 4 ? 45 : 13, NHEAD, BB), 256, 0, stream>>>(
            qkh, qkl, vth, vtl, atth, attl,
            l < 4 ? qkv_w + (size_t)lnx * 512 * 1536 : nullptr,
            l < 4 ? attn_out_w + (size_t)lnx * 512 * 512 : nullptr,
            l < 4 ? ff1_w + (size_t)lnx * 512 * 1024 : nullptr,
            l < 4 ? ff2_w + (size_t)lnx * 1024 * 512 : nullptr,
            nth, ntl);
        gemm_mfma<64, 3><<<dim3(512 / 64, MB), 256, 0, stream>>>(
            atth, attl, wth + 786432, wtl + 786432, attn_out_b + ln2off, xbuf,
            xbuf, nullptr, nullptr, nullptr, nullptr, NROWS, 512, 512);
        ln_kernel<<<NROWS, 64, 0, stream>>>(xbuf, ln2_g + ln2off, ln2_b + ln2off, xnh, xnl);
        gemm_mfma<128, 2><<<dim3(1024 / 128, MB), 256, 0, stream>>>(
            xnh, xnl, wth + 1048576, wtl + 1048576, ff1_b + l * 1024, nullptr,
            nullptr, ffhh, ffhl, nullptr, nullptr, NROWS, 1024, 512);
        gemm_mfma<64, 3><<<dim3(512 / 64, MB), 256, 0, stream>>>(
            ffhh, ffhl, wth + 1572864, wtl + 1572864, ff2_b + ln2off, xbuf,
            xbuf, nullptr, nullptr, nullptr, nullptr, NROWS, 512, 1024);
    }
    pool_max_kernel<<<dim3(13, BB), 512, 0, stream>>>(xbuf, ppart);
    pool_ln_kernel<<<BB, 512, 0, stream>>>(ppart, head_ln_g, head_ln_b, pooled);
    head1_kernel<<<dim3(16, BB), 256, 0, stream>>>(pooled, head1_w, head1_b, h1);
    head2_kernel<<<dim3(17, BB), 256, 0, stream>>>(h1, head2_w, head2_b, h2);
    smax_anchor_kernel<<<BB * 17, 64, 0, stream>>>(h2, (float*)d_out);
}

// Round 12
// 2011.718 us; speedup vs baseline: 1.4043x; 1.4043x over previous
//
#include <hip/hip_runtime.h>
#include <hip/hip_bf16.h>
#include <cstddef>

// Problem constants
#define BB 8
#define LL 5
#define NN 4096
#define NANCH 64
#define NPTS 4160      // NN + NANCH
#define MM 260         // NPTS / 16
#define NFRAME 3
#define SSEQ 780       // NFRAME * MM
#define DIMC 512
#define NHEAD 8
#define DHEAD 64
#define MLPD 1024
#define OUTD 1088
#define NROWS 6240     // BB * SSEQ
#define VPITCH 784     // vT key pitch (780 padded to 16B-aligned rows)
#define WBUFSZ 2097152 // ushorts per weight buffer (qkv|proj|ff1|ff2)

typedef __attribute__((ext_vector_type(8))) short s16x8;
typedef __attribute__((ext_vector_type(4))) float fx4;
typedef unsigned short ushort_t;
typedef unsigned int uint_t;

// exact (non-contracted) squared distance, matching numpy fp32 op order
__device__ __forceinline__ float sqdist_rn(float x1, float y1, float z1,
                                           float x2, float y2, float z2) {
    float dx = __fsub_rn(x1, x2);
    float dy = __fsub_rn(y1, y2);
    float dz = __fsub_rn(z1, z2);
    return __fadd_rn(__fadd_rn(__fmul_rn(dx, dx), __fmul_rn(dy, dy)), __fmul_rn(dz, dz));
}

__device__ __forceinline__ float gelu_exact(float v) {
    return 0.5f * v * (1.0f + erff(v * 0.70710678118654752440f));
}

// round-to-nearest bf16
__device__ __forceinline__ uint_t bf16rn(float f) {
    uint_t u = __float_as_uint(f);
    return (u + 0x7FFFu + ((u >> 16) & 1u)) >> 16;
}
// split fp32 into bf16 hi + bf16 lo (residual)
__device__ __forceinline__ void split2(float f, ushort_t& h, ushort_t& l) {
    uint_t hb = bf16rn(f);
    h = (ushort_t)hb;
    float fh = __uint_as_float(hb << 16);
    l = (ushort_t)bf16rn(f - fh);
}

// ---- DPP wave64 reductions. ctrl must be an immediate -> template param.
template <int CTRL>
__device__ __forceinline__ int dpp_mov(int v) {
    return __builtin_amdgcn_update_dpp(0, v, CTRL, 0xF, 0xF, true);
}
#define DPP_STEP_F(op, v, ctrl) v = op(v, __int_as_float(dpp_mov<ctrl>(__float_as_int(v))))
__device__ __forceinline__ float wave_max_bcast(float v) {
    DPP_STEP_F(fmaxf, v, 0x111); DPP_STEP_F(fmaxf, v, 0x112);
    DPP_STEP_F(fmaxf, v, 0x114); DPP_STEP_F(fmaxf, v, 0x118);
    DPP_STEP_F(fmaxf, v, 0x142); DPP_STEP_F(fmaxf, v, 0x143);
    return __int_as_float(__builtin_amdgcn_readlane(__float_as_int(v), 63));
}
__device__ __forceinline__ float faddf(float a, float b) { return a + b; }
__device__ __forceinline__ float wave_sum_bcast(float v) {
    DPP_STEP_F(faddf, v, 0x111); DPP_STEP_F(faddf, v, 0x112);
    DPP_STEP_F(faddf, v, 0x114); DPP_STEP_F(faddf, v, 0x118);
    DPP_STEP_F(faddf, v, 0x142); DPP_STEP_F(faddf, v, 0x143);
    return __int_as_float(__builtin_amdgcn_readlane(__float_as_int(v), 63));
}
#define DPP_STEP_I(v, ctrl) { int _x = dpp_mov<ctrl>(v); v = v > _x ? v : _x; }
__device__ __forceinline__ int wave_maxi_bcast(int v) {
    DPP_STEP_I(v, 0x111); DPP_STEP_I(v, 0x112);
    DPP_STEP_I(v, 0x114); DPP_STEP_I(v, 0x118);
    DPP_STEP_I(v, 0x142); DPP_STEP_I(v, 0x143);
    return __builtin_amdgcn_readlane(v, 63);
}
// 16-entry reduce within a DPP row; result broadcast from lane 15.
__device__ __forceinline__ float row16_maxf(float v) {
    DPP_STEP_F(fmaxf, v, 0x111); DPP_STEP_F(fmaxf, v, 0x112);
    DPP_STEP_F(fmaxf, v, 0x114); DPP_STEP_F(fmaxf, v, 0x118);
    return __int_as_float(__builtin_amdgcn_readlane(__float_as_int(v), 15));
}
__device__ __forceinline__ int row16_maxi(int v) {
    DPP_STEP_I(v, 0x111); DPP_STEP_I(v, 0x112);
    DPP_STEP_I(v, 0x114); DPP_STEP_I(v, 0x118);
    return __builtin_amdgcn_readlane(v, 15);
}

// ---------------------------------------------------------------------------
// Generic weight transpose + bf16 split, one 32x32 tile per call.
// ---------------------------------------------------------------------------
__device__ __forceinline__ void wsplit_tile(
    int bid, int tid, int nthr,
    const float* __restrict__ qkvw, const float* __restrict__ projw,
    const float* __restrict__ ff1w, const float* __restrict__ ff2w,
    ushort_t* __restrict__ th, ushort_t* __restrict__ tl,
    float (*T)[33]) {
    const float* src; int K, N; size_t dst;
    if (bid < 768)       { src = qkvw;  K = 512;  N = 1536; dst = 0;       }
    else if (bid < 1024) { src = projw; K = 512;  N = 512;  dst = 786432;  bid -= 768;  }
    else if (bid < 1536) { src = ff1w;  K = 512;  N = 1024; dst = 1048576; bid -= 1024; }
    else                 { src = ff2w;  K = 1024; N = 512;  dst = 1572864; bid -= 1536; }
    int ntn = N >> 5;
    int tn = bid % ntn, tk = bid / ntn;
    int n0 = tn * 32, k0 = tk * 32;
    for (int e = tid; e < 1024; e += nthr) {
        int r = e >> 5, c = e & 31;
        T[r][c] = src[(size_t)(k0 + r) * N + n0 + c];
    }
    __syncthreads();
    for (int e = tid; e < 1024; e += nthr) {
        int r = e >> 5, c = e & 31;
        ushort_t h, l;
        split2(T[c][r], h, l);
        th[dst + (size_t)(n0 + r) * K + k0 + c] = h;
        tl[dst + (size_t)(n0 + r) * K + k0 + c] = l;
    }
}

// ---------------------------------------------------------------------------
__global__ __launch_bounds__(256) void build_pts_kernel(const float* __restrict__ points,
                                                        float* __restrict__ pts) {
    int i = blockIdx.x * 256 + threadIdx.x;   // over B*L*NPTS = 166400
    if (i >= BB * LL * NPTS) return;
    int n = i % NPTS;
    int bl = i / NPTS;
    if (n < NN) {
        const float* src = points + ((size_t)bl * NN + n) * 3;
        pts[(size_t)i * 3 + 0] = src[0];
        pts[(size_t)i * 3 + 1] = src[1];
        pts[(size_t)i * 3 + 2] = src[2];
    } else {
        int j = n - NN;
        int ix = j >> 4, iy = (j >> 2) & 3, iz = j & 3;
        pts[(size_t)i * 3 + 0] = -1.5f + (float)ix;
        pts[(size_t)i * 3 + 1] = -1.5f + (float)iy;
        pts[(size_t)i * 3 + 2] = -1.5f + (float)iz;
    }
}

// ---------------------------------------------------------------------------
// FPS (blocks 0..23, 1024 thr, 16 waves) + layer-0 wsplit (blocks 24..2071).
// ---------------------------------------------------------------------------
__global__ __launch_bounds__(1024) void fps_ws_kernel(
    const float* __restrict__ pts, float* __restrict__ axyz,
    const float* __restrict__ qkvw, const float* __restrict__ projw,
    const float* __restrict__ ff1w, const float* __restrict__ ff2w,
    ushort_t* __restrict__ th, ushort_t* __restrict__ tl) {
    __shared__ __align__(16) char smem[50432];
    int bid = blockIdx.x;
    int tid = threadIdx.x;
    if (bid >= 24) {
        wsplit_tile(bid - 24, tid, 1024, qkvw, projw, ff1w, ff2w, th, tl,
                    (float(*)[33])smem);
        return;
    }
    float* sx = (float*)smem;
    float* sy = sx + NPTS;
    float* sz = sy + NPTS;
    float* redv = sz + NPTS;          // [2][16]
    int* redi = (int*)(redv + 32);    // [2][16]

    int b = bid / 3, f = bid % 3;
    const float* P = pts + (size_t)(b * LL + 2 * f) * NPTS * 3;
    int lane = tid & 63, wid = tid >> 6;
    const int PPT = 5;                // ceil(4160/1024)
    float px[PPT], py[PPT], pz[PPT], dist[PPT];
#pragma unroll
    for (int j = 0; j < PPT; j++) {
        int n = tid + 1024 * j;
        if (n < NPTS) {
            float gx = P[(size_t)n * 3 + 0];
            float gy = P[(size_t)n * 3 + 1];
            float gz = P[(size_t)n * 3 + 2];
            px[j] = gx; py[j] = gy; pz[j] = gz;
            sx[n] = gx; sy[n] = gy; sz[n] = gz;
            dist[j] = 1e10f;
        } else {
            px[j] = 0.f; py[j] = 0.f; pz[j] = 0.f;
            dist[j] = -1.0f;          // never selected
        }
    }
    __syncthreads();
    float ax = sx[0], ay = sy[0], az = sz[0];
    float* out = axyz + (size_t)bid * MM * 3;
    for (int m = 0; m < MM; m++) {
        if (tid == 0) { out[m * 3 + 0] = ax; out[m * 3 + 1] = ay; out[m * 3 + 2] = az; }
        float bestv = -1.0f;
        int bestn = NPTS;
#pragma unroll
        for (int j = 0; j < PPT; j++) {
            int n = tid + 1024 * j;
            if (n < NPTS) {
                float d = sqdist_rn(px[j], py[j], pz[j], ax, ay, az);
                float dj = fminf(dist[j], d);
                dist[j] = dj;
                if (dj > bestv) { bestv = dj; bestn = n; }  // ascending n: keeps first
            }
        }
        float wm = wave_max_bcast(bestv);
        int wn = 0x7FFFFFFF - wave_maxi_bcast(bestv == wm ? (0x7FFFFFFF - bestn) : 0);
        int par = (m & 1) * 16;
        if (lane == 0) { redv[par + wid] = wm; redi[par + wid] = wn; }
        __syncthreads();
        float cv = redv[par + (lane & 15)];
        int ci = redi[par + (lane & 15)];
        float bv = row16_maxf(cv);
        int bn = 0x7FFFFFFF - row16_maxi(cv == bv ? (0x7FFFFFFF - ci) : 0);
        ax = sx[bn]; ay = sy[bn]; az = sz[bn];
    }
}

// ---------------------------------------------------------------------------
// Ball query + grouped conv + max over k + max over window + pos embedding.
// ---------------------------------------------------------------------------
__global__ __launch_bounds__(64) void group_conv_kernel(
    const float* __restrict__ pts, const float* __restrict__ axyz,
    const float* __restrict__ conv_d_w, const float* __restrict__ conv_f_w,
    const float* __restrict__ pos_w, const float* __restrict__ pos_b,
    float* __restrict__ x) {
    int gid = blockIdx.x;                 // b*780 + f*260 + m
    int b = gid / SSEQ;
    int rem = gid % SSEQ;
    int f = rem / MM;
    int lane = threadIdx.x;
    const float* A = axyz + (size_t)gid * 3;
    float ax = A[0], ay = A[1], az = A[2];

    float cf0[8], cf1[8], cf2[8], cd0[8], cd1[8], cd2[8], cd3[8], fmx[8];
#pragma unroll
    for (int c = 0; c < 8; c++) {
        int d = lane + 64 * c;
        cf0[c] = conv_f_w[d * 3 + 0];
        cf1[c] = conv_f_w[d * 3 + 1];
        cf2[c] = conv_f_w[d * 3 + 2];
        cd0[c] = conv_d_w[d * 4 + 0];
        cd1[c] = conv_d_w[d * 4 + 1];
        cd2[c] = conv_d_w[d * 4 + 2];
        cd3[c] = conv_d_w[d * 4 + 3];
        fmx[c] = -INFINITY;
    }
    __shared__ int nbr[32];
    __shared__ float gxs[32], gys[32], gzs[32];
    const float R2 = 0.49000000953674316f;

    for (int wi = 0; wi < 3; wi++) {
        int l = 2 * f + wi - 1;
        l = l < 0 ? 0 : (l > 4 ? 4 : l);
        const float* P = pts + (size_t)(b * LL + l) * NPTS * 3;
        int cnt = 0;
        for (int base = 0; base < NPTS && cnt < 32; base += 64) {
            int n = base + lane;
            float d2 = sqdist_rn(P[(size_t)n * 3], P[(size_t)n * 3 + 1], P[(size_t)n * 3 + 2],
                                 ax, ay, az);
            bool hit = d2 < R2;
            unsigned long long mk = __ballot(hit);
            int rank = (int)__popcll(mk & (((unsigned long long)1 << lane) - 1ull));
            if (hit && (cnt + rank) < 32) nbr[cnt + rank] = n;
            cnt += (int)__popcll(mk);
        }
        __syncthreads();
        int eff = cnt < 32 ? cnt : 32;
        if (lane < 32) {
            int idx = (eff == 0) ? 0 : (lane < eff ? nbr[lane] : nbr[0]);
            gxs[lane] = P[(size_t)idx * 3 + 0];
            gys[lane] = P[(size_t)idx * 3 + 1];
            gzs[lane] = P[(size_t)idx * 3 + 2];
        }
        __syncthreads();
        float tf = (float)(wi - 1);
        for (int k = 0; k < 32; k++) {
            float gx = gxs[k], gy = gys[k], gz = gzs[k];
            float dx = gx - ax, dy = gy - ay, dz = gz - az;
#pragma unroll
            for (int c = 0; c < 8; c++) {
                float v = gx * cf0[c] + gy * cf1[c] + gz * cf2[c] +
                          dx * cd0[c] + dy * cd1[c] + dz * cd2[c] + tf * cd3[c];
                fmx[c] = fmaxf(fmx[c], v);
            }
        }
        __syncthreads();
    }
    float tcol = (float)(f + 1);
#pragma unroll
    for (int c = 0; c < 8; c++) {
        int d = lane + 64 * c;
        float pos = ax * pos_w[d * 4 + 0] + ay * pos_w[d * 4 + 1] +
                    az * pos_w[d * 4 + 2] + tcol * pos_w[d * 4 + 3] + pos_b[d];
        x[(size_t)gid * DIMC + d] = fmx[c] + pos;
    }
}

// ---------------------------------------------------------------------------
// LayerNorm over last dim 512; output written as bf16 hi/lo split (GEMM A).
// ---------------------------------------------------------------------------
__global__ __launch_bounds__(64) void ln_kernel(const float* __restrict__ x,
                                                const float* __restrict__ g,
                                                const float* __restrict__ b,
                                                ushort_t* __restrict__ yh,
                                                ushort_t* __restrict__ yl) {
    int r = blockIdx.x;
    int lane = threadIdx.x;
    const float* xr = x + (size_t)r * DIMC;
    float4 v0 = *(const float4*)(xr + lane * 8);
    float4 v1 = *(const float4*)(xr + lane * 8 + 4);
    float s = v0.x + v0.y + v0.z + v0.w + v1.x + v1.y + v1.z + v1.w;
    s = wave_sum_bcast(s);
    float mean = s * (1.0f / 512.0f);
    float dv[8];
    dv[0] = v0.x - mean; dv[1] = v0.y - mean; dv[2] = v0.z - mean; dv[3] = v0.w - mean;
    dv[4] = v1.x - mean; dv[5] = v1.y - mean; dv[6] = v1.z - mean; dv[7] = v1.w - mean;
    float sq = 0.f;
#pragma unroll
    for (int c = 0; c < 8; c++) sq += dv[c] * dv[c];
    sq = wave_sum_bcast(sq);
    float var = sq * (1.0f / 512.0f);
    float inv = 1.0f / sqrtf(var + 1e-5f);
    int d = lane * 8;
    ushort_t hs[8], ls[8];
#pragma unroll
    for (int c = 0; c < 8; c++) {
        float v = dv[c] * inv * g[d + c] + b[d + c];
        split2(v, hs[c], ls[c]);
    }
    uint4 hv, lv;
    hv.x = hs[0] | ((uint_t)hs[1] << 16); hv.y = hs[2] | ((uint_t)hs[3] << 16);
    hv.z = hs[4] | ((uint_t)hs[5] << 16); hv.w = hs[6] | ((uint_t)hs[7] << 16);
    lv.x = ls[0] | ((uint_t)ls[1] << 16); lv.y = ls[2] | ((uint_t)ls[3] << 16);
    lv.z = ls[4] | ((uint_t)ls[5] << 16); lv.w = ls[6] | ((uint_t)ls[7] << 16);
    *(uint4*)(yh + (size_t)r * DIMC + d) = hv;
    *(uint4*)(yl + (size_t)r * DIMC + d) = lv;
}

// ---------------------------------------------------------------------------
// bf16x3 MFMA GEMM (fp32 emulation): C = A @ W.
// R9 LDS structure + register-prefetch software pipeline: global loads for
// k+1 issue right after the staging barrier and are committed to LDS at the
// next iteration's top, hiding L2 latency behind the 48 MFMAs of step k.
// EPI: 0 = fp32 C; 2 = bias+gelu -> split (Ch,Cl); 3 = bias+R -> C;
//      5 = qkv: Q/K cols -> split (Ch,Cl) stride 1024; V cols -> transposed
//          vT[(b*8+h)*64+d][key] split (Vh,Vl), key pitch VPITCH.
// ---------------------------------------------------------------------------
#define KP 40   // LDS row pitch in ushorts

template <int BN, int EPI>
__global__ __launch_bounds__(256, 2) void gemm_mfma(
    const ushort_t* __restrict__ Ahg, const ushort_t* __restrict__ Alg,
    const ushort_t* __restrict__ Bhg, const ushort_t* __restrict__ Blg,
    const float* __restrict__ bias, const float* __restrict__ R,
    float* __restrict__ C, ushort_t* __restrict__ Ch, ushort_t* __restrict__ Cl,
    ushort_t* __restrict__ Vh, ushort_t* __restrict__ Vl,
    int M, int N, int K) {
    const int WN = BN / 2, NT = WN / 16;
    __shared__ ushort_t Ah[128 * KP];
    __shared__ ushort_t Al[128 * KP];
    __shared__ ushort_t Bh[BN * KP];
    __shared__ ushort_t Bl[BN * KP];
    int tid = threadIdx.x;
    int lane = tid & 63, w = tid >> 6;
    int wm = w & 1, wn = w >> 1;
    int quad = lane >> 4, l15 = lane & 15;
    int m0 = blockIdx.y * 128, n0 = blockIdx.x * BN;

    // staging slots: thread handles rows (sa_row, sa_row+64) at k-chunk sa_k
    int sa_row = tid >> 2;            // 0..63
    int sa_k = (tid & 3) * 8;         // 0,8,16,24

    int row_a0 = m0 + sa_row;       if (row_a0 >= M) row_a0 = M - 1;
    int row_a1 = m0 + sa_row + 64;  if (row_a1 >= M) row_a1 = M - 1;
    const ushort_t* pAh0 = Ahg + (size_t)row_a0 * K + sa_k;
    const ushort_t* pAl0 = Alg + (size_t)row_a0 * K + sa_k;
    const ushort_t* pAh1 = Ahg + (size_t)row_a1 * K + sa_k;
    const ushort_t* pAl1 = Alg + (size_t)row_a1 * K + sa_k;
    const ushort_t* pBh0 = Bhg + (size_t)(n0 + sa_row) * K + sa_k;
    const ushort_t* pBl0 = Blg + (size_t)(n0 + sa_row) * K + sa_k;
    const ushort_t* pBh1 = (BN == 128) ? Bhg + (size_t)(n0 + sa_row + 64) * K + sa_k : pBh0;
    const ushort_t* pBl1 = (BN == 128) ? Blg + (size_t)(n0 + sa_row + 64) * K + sa_k : pBl0;

    fx4 acc[4][NT];
#pragma unroll
    for (int mi = 0; mi < 4; mi++)
#pragma unroll
        for (int nj = 0; nj < NT; nj++) acc[mi][nj] = (fx4){0.f, 0.f, 0.f, 0.f};

    // prefetch k0 = 0
    float4 ra0h = *(const float4*)pAh0, ra0l = *(const float4*)pAl0;
    float4 ra1h = *(const float4*)pAh1, ra1l = *(const float4*)pAl1;
    float4 rb0h = *(const float4*)pBh0, rb0l = *(const float4*)pBl0;
    float4 rb1h, rb1l;
    if (BN == 128) { rb1h = *(const float4*)pBh1; rb1l = *(const float4*)pBl1; }

    for (int k0 = 0; k0 < K; k0 += 32) {
        // commit prefetched regs to LDS
        *(float4*)&Ah[sa_row * KP + sa_k] = ra0h;
        *(float4*)&Al[sa_row * KP + sa_k] = ra0l;
        *(float4*)&Ah[(sa_row + 64) * KP + sa_k] = ra1h;
        *(float4*)&Al[(sa_row + 64) * KP + sa_k] = ra1l;
        *(float4*)&Bh[sa_row * KP + sa_k] = rb0h;
        *(float4*)&Bl[sa_row * KP + sa_k] = rb0l;
        if (BN == 128) {
            *(float4*)&Bh[(sa_row + 64) * KP + sa_k] = rb1h;
            *(float4*)&Bl[(sa_row + 64) * KP + sa_k] = rb1l;
        }
        __syncthreads();
        // prefetch next k-step (overlaps with fragment reads + MFMAs below)
        int kn = k0 + 32;
        if (kn < K) {
            ra0h = *(const float4*)(pAh0 + kn); ra0l = *(const float4*)(pAl0 + kn);
            ra1h = *(const float4*)(pAh1 + kn); ra1l = *(const float4*)(pAl1 + kn);
            rb0h = *(const float4*)(pBh0 + kn); rb0l = *(const float4*)(pBl0 + kn);
            if (BN == 128) {
                rb1h = *(const float4*)(pBh1 + kn); rb1l = *(const float4*)(pBl1 + kn);
            }
        }
        s16x8 af[4][2], bf[NT][2];
#pragma unroll
        for (int mi = 0; mi < 4; mi++) {
            int off = (64 * wm + 16 * mi + l15) * KP + quad * 8;
            af[mi][0] = *(const s16x8*)&Ah[off];
            af[mi][1] = *(const s16x8*)&Al[off];
        }
#pragma unroll
        for (int nj = 0; nj < NT; nj++) {
            int off = (WN * wn + 16 * nj + l15) * KP + quad * 8;
            bf[nj][0] = *(const s16x8*)&Bh[off];
            bf[nj][1] = *(const s16x8*)&Bl[off];
        }
#pragma unroll
        for (int mi = 0; mi < 4; mi++)
#pragma unroll
            for (int nj = 0; nj < NT; nj++) {
                acc[mi][nj] = __builtin_amdgcn_mfma_f32_16x16x32_bf16(af[mi][0], bf[nj][0], acc[mi][nj], 0, 0, 0);
                acc[mi][nj] = __builtin_amdgcn_mfma_f32_16x16x32_bf16(af[mi][0], bf[nj][1], acc[mi][nj], 0, 0, 0);
                acc[mi][nj] = __builtin_amdgcn_mfma_f32_16x16x32_bf16(af[mi][1], bf[nj][0], acc[mi][nj], 0, 0, 0);
            }
        __syncthreads();
    }
#pragma unroll
    for (int mi = 0; mi < 4; mi++) {
#pragma unroll
        for (int r = 0; r < 4; r++) {
            int row = m0 + 64 * wm + 16 * mi + quad * 4 + r;
            if (row < M) {
#pragma unroll
                for (int nj = 0; nj < NT; nj++) {
                    int col = n0 + WN * wn + 16 * nj + l15;
                    float v = acc[mi][nj][r];
                    if (EPI == 0) {
                        C[(size_t)row * N + col] = v;
                    } else if (EPI == 3) {
                        C[(size_t)row * N + col] = v + bias[col] + R[(size_t)row * N + col];
                    } else if (EPI == 2) {
                        float gv = gelu_exact(v + bias[col]);
                        ushort_t h, l;
                        split2(gv, h, l);
                        Ch[(size_t)row * N + col] = h;
                        Cl[(size_t)row * N + col] = l;
                    } else if (EPI == 5) {
                        ushort_t h, l;
                        split2(v, h, l);
                        if (col < 1024) {
                            Ch[(size_t)row * 1024 + col] = h;
                            Cl[(size_t)row * 1024 + col] = l;
                        } else {
                            int bb = row / SSEQ, key = row % SSEQ;
                            int hh = (col - 1024) >> 6, dd = (col - 1024) & 63;
                            size_t vo = ((size_t)((bb * 8 + hh) * 64 + dd)) * VPITCH + key;
                            Vh[vo] = h;
                            Vl[vo] = l;
                        }
                    }
                }
            }
        }
    }
}

// ---------------------------------------------------------------------------
// MFMA flash attention (blocks x<13) + next-layer wsplit (blocks x>=13).
// ---------------------------------------------------------------------------
#define AP 72   // ushort pitch

__global__ __launch_bounds__(256, 2) void attn_mfma_kernel(
    const ushort_t* __restrict__ qkh, const ushort_t* __restrict__ qkl,
    const ushort_t* __restrict__ vth, const ushort_t* __restrict__ vtl,
    ushort_t* __restrict__ oh, ushort_t* __restrict__ ol,
    const float* __restrict__ nqkvw, const float* __restrict__ nprojw,
    const float* __restrict__ nff1w, const float* __restrict__ nff2w,
    ushort_t* __restrict__ nth, ushort_t* __restrict__ ntl) {
    __shared__ __align__(16) char smem[73728];
    if (blockIdx.x >= 13) {
        int widx = (blockIdx.x - 13) * 64 + blockIdx.y * 8 + blockIdx.z;
        wsplit_tile(widx, threadIdx.x, 256, nqkvw, nprojw, nff1w, nff2w,
                    nth, ntl, (float(*)[33])smem);
        return;
    }
    ushort_t* Qh  = (ushort_t*)smem;
    ushort_t* Ql  = Qh + 64 * AP;
    ushort_t* Kh  = Ql + 64 * AP;
    ushort_t* Kl  = Kh + 64 * AP;
    ushort_t* Vth = Kl + 64 * AP;
    ushort_t* Vtl = Vth + 64 * AP;
    ushort_t* Ph  = Vtl + 64 * AP;
    ushort_t* Pl  = Ph + 64 * AP;

    int qt = blockIdx.x, h = blockIdx.y, b = blockIdx.z;
    int tid = threadIdx.x;
    int lane = tid & 63, w = tid >> 6;
    int quad = lane >> 4, l15 = lane & 15;
    int bh = b * 8 + h;

    int q0 = qt * 64;
    int nq = SSEQ - q0; if (nq > 64) nq = 64;

    // stage Q (hi/lo), rows clamped
#pragma unroll
    for (int i = 0; i < 2; i++) {
        int t = tid + 256 * i;
        int row = t >> 3, c = (t & 7) * 8;
        int gq = q0 + (row < nq ? row : nq - 1);
        size_t go = (size_t)(b * SSEQ + gq) * 1024 + h * 64 + c;
        *(uint4*)&Qh[row * AP + c] = *(const uint4*)(qkh + go);
        *(uint4*)&Ql[row * AP + c] = *(const uint4*)(qkl + go);
    }

    fx4 accO[4];
#pragma unroll
    for (int dj = 0; dj < 4; dj++) accO[dj] = (fx4){0.f, 0.f, 0.f, 0.f};
    fx4 accL = (fx4){0.f, 0.f, 0.f, 0.f};

    s16x8 ones;
#pragma unroll
    for (int j = 0; j < 8; j++) ones[j] = (short)16256;   // bf16 1.0

    for (int kt = 0; kt < 13; kt++) {
        int k0 = kt * 64;
        int nk = SSEQ - k0; if (nk > 64) nk = 64;
        __syncthreads();   // prior QK/PV reads done before overwrite
#pragma unroll
        for (int i = 0; i < 2; i++) {
            int t = tid + 256 * i;
            int row = t >> 3, c = (t & 7) * 8;
            int gk = k0 + (row < nk ? row : nk - 1);
            size_t go = (size_t)(b * SSEQ + gk) * 1024 + h * 64 + c;
            *(uint4*)&Kh[row * AP + c] = *(const uint4*)(qkh + go + 512);
            *(uint4*)&Kl[row * AP + c] = *(const uint4*)(qkl + go + 512);
            size_t vo = ((size_t)(bh * 64 + row)) * VPITCH + k0 + c;
            *(uint4*)&Vth[row * AP + c] = *(const uint4*)(vth + vo);
            *(uint4*)&Vtl[row * AP + c] = *(const uint4*)(vtl + vo);
        }
        __syncthreads();

        // S = Q K^T (x3): wave's 16 q rows x 64 keys
        fx4 accS[4];
#pragma unroll
        for (int nj = 0; nj < 4; nj++) accS[nj] = (fx4){0.f, 0.f, 0.f, 0.f};
#pragma unroll
        for (int ks = 0; ks < 2; ks++) {
            s16x8 aH = *(const s16x8*)&Qh[(16 * w + l15) * AP + 32 * ks + quad * 8];
            s16x8 aL = *(const s16x8*)&Ql[(16 * w + l15) * AP + 32 * ks + quad * 8];
#pragma unroll
            for (int nj = 0; nj < 4; nj++) {
                s16x8 bH = *(const s16x8*)&Kh[(16 * nj + l15) * AP + 32 * ks + quad * 8];
                s16x8 bL = *(const s16x8*)&Kl[(16 * nj + l15) * AP + 32 * ks + quad * 8];
                accS[nj] = __builtin_amdgcn_mfma_f32_16x16x32_bf16(aH, bH, accS[nj], 0, 0, 0);
                accS[nj] = __builtin_amdgcn_mfma_f32_16x16x32_bf16(aH, bL, accS[nj], 0, 0, 0);
                accS[nj] = __builtin_amdgcn_mfma_f32_16x16x32_bf16(aL, bH, accS[nj], 0, 0, 0);
            }
        }
        // P = exp(S * scale), split hi/lo, write to wave-local LDS region
#pragma unroll
        for (int nj = 0; nj < 4; nj++) {
            int key = 16 * nj + l15;
            bool valid = key < nk;
#pragma unroll
            for (int r = 0; r < 4; r++) {
                float s = accS[nj][r] * 0.125f;
                float p = valid ? __expf(s) : 0.f;
                ushort_t hh, ll;
                split2(p, hh, ll);
                int qrow = 16 * w + quad * 4 + r;
                Ph[qrow * AP + key] = hh;
                Pl[qrow * AP + key] = ll;
            }
        }
        // PV (x3) + l-sum (ones-B); wave-local, in-order DS => no barrier
#pragma unroll
        for (int ks = 0; ks < 2; ks++) {
            s16x8 aPh = *(const s16x8*)&Ph[(16 * w + l15) * AP + 32 * ks + quad * 8];
            s16x8 aPl = *(const s16x8*)&Pl[(16 * w + l15) * AP + 32 * ks + quad * 8];
            accL = __builtin_amdgcn_mfma_f32_16x16x32_bf16(aPh, ones, accL, 0, 0, 0);
            accL = __builtin_amdgcn_mfma_f32_16x16x32_bf16(aPl, ones, accL, 0, 0, 0);
#pragma unroll
            for (int dj = 0; dj < 4; dj++) {
                s16x8 bVh = *(const s16x8*)&Vth[(16 * dj + l15) * AP + 32 * ks + quad * 8];
                s16x8 bVl = *(const s16x8*)&Vtl[(16 * dj + l15) * AP + 32 * ks + quad * 8];
                accO[dj] = __builtin_amdgcn_mfma_f32_16x16x32_bf16(aPh, bVh, accO[dj], 0, 0, 0);
                accO[dj] = __builtin_amdgcn_mfma_f32_16x16x32_bf16(aPh, bVl, accO[dj], 0, 0, 0);
                accO[dj] = __builtin_amdgcn_mfma_f32_16x16x32_bf16(aPl, bVh, accO[dj], 0, 0, 0);
            }
        }
    }
    // store O / l ; rows of accL align with rows of accO (C-layout)
#pragma unroll
    for (int r = 0; r < 4; r++) {
        int lq = 16 * w + quad * 4 + r;
        if (lq < nq) {
            float inv = 1.0f / accL[r];
            size_t base = (size_t)(b * SSEQ + q0 + lq) * DIMC + h * 64 + l15;
#pragma unroll
            for (int dj = 0; dj < 4; dj++) {
                ushort_t hh, ll;
                split2(accO[dj][r] * inv, hh, ll);
                oh[base + 16 * dj] = hh;
                ol[base + 16 * dj] = ll;
            }
        }
    }
}

// ---------------------------------------------------------------------------
// Head: two-stage max-pool + LN, then parallel head GEMVs (fp32).
// ---------------------------------------------------------------------------
__global__ __launch_bounds__(512) void pool_max_kernel(const float* __restrict__ x,
                                                       float* __restrict__ partial) {
    int c = blockIdx.x;        // 0..12 (chunks of 60 rows)
    int bb = blockIdx.y;
    int d = threadIdx.x;
    const float* xb = x + ((size_t)(bb * SSEQ + c * 60)) * DIMC + d;
    float m = -INFINITY;
#pragma unroll 4
    for (int s = 0; s < 60; s++) m = fmaxf(m, xb[(size_t)s * DIMC]);
    partial[((size_t)bb * 13 + c) * DIMC + d] = m;
}

__global__ __launch_bounds__(512) void pool_ln_kernel(const float* __restrict__ partial,
                                                      const float* __restrict__ g,
                                                      const float* __restrict__ b,
                                                      float* __restrict__ out) {
    int bb = blockIdx.x;
    int d = threadIdx.x;
    const float* pb = partial + (size_t)bb * 13 * DIMC + d;
    float m = -INFINITY;
#pragma unroll
    for (int c = 0; c < 13; c++) m = fmaxf(m, pb[(size_t)c * DIMC]);
    __shared__ float col[512];
    __shared__ float red[512];
    col[d] = m;
    red[d] = m;
    __syncthreads();
    for (int s = 256; s > 0; s >>= 1) {
        if (d < s) red[d] += red[d + s];
        __syncthreads();
    }
    float mean = red[0] * (1.0f / 512.0f);
    __syncthreads();
    float dv = col[d] - mean;
    red[d] = dv * dv;
    __syncthreads();
    for (int s = 256; s > 0; s >>= 1) {
        if (d < s) red[d] += red[d + s];
        __syncthreads();
    }
    float var = red[0] * (1.0f / 512.0f);
    float inv = 1.0f / sqrtf(var + 1e-5f);
    out[(size_t)bb * DIMC + d] = dv * inv * g[d] + b[d];
}

__global__ __launch_bounds__(256) void head1_kernel(const float* __restrict__ in,
                                                    const float* __restrict__ W,
                                                    const float* __restrict__ bias,
                                                    float* __restrict__ out) {
    int g = blockIdx.x, bb = blockIdx.y;
    int tid = threadIdx.x;
    int c = tid & 63, ks = tid >> 6;
    int col = g * 64 + c;
    __shared__ float xr[512];
    xr[tid] = in[(size_t)bb * 512 + tid];
    xr[tid + 256] = in[(size_t)bb * 512 + tid + 256];
    __syncthreads();
    float acc = 0.f;
    const float* Wc = W + col;
    for (int k = ks * 128; k < ks * 128 + 128; k++)
        acc += xr[k] * Wc[(size_t)k * MLPD];
    __shared__ float red[256];
    red[tid] = acc;
    __syncthreads();
    if (ks == 0) {
        float v = red[c] + red[c + 64] + red[c + 128] + red[c + 192] + bias[col];
        out[(size_t)bb * MLPD + col] = gelu_exact(v);
    }
}

__global__ __launch_bounds__(256) void head2_kernel(const float* __restrict__ in,
                                                    const float* __restrict__ W,
                                                    const float* __restrict__ bias,
                                                    float* __restrict__ out) {
    int g = blockIdx.x, bb = blockIdx.y;
    int tid = threadIdx.x;
    int c = tid & 63, ks = tid >> 6;
    int col = g * 64 + c;
    __shared__ float xr[1024];
    xr[tid] = in[(size_t)bb * 1024 + tid];
    xr[tid + 256] = in[(size_t)bb * 1024 + tid + 256];
    xr[tid + 512] = in[(size_t)bb * 1024 + tid + 512];
    xr[tid + 768] = in[(size_t)bb * 1024 + tid + 768];
    __syncthreads();
    float acc = 0.f;
    const float* Wc = W + col;
    for (int k = ks * 256; k < ks * 256 + 256; k++)
        acc += xr[k] * Wc[(size_t)k * OUTD];
    __shared__ float red[256];
    red[tid] = acc;
    __syncthreads();
    if (ks == 0) {
        out[(size_t)bb * OUTD + col] = red[c] + red[c + 64] + red[c + 128] + red[c + 192] + bias[col];
    }
}

__global__ __launch_bounds__(64) void smax_anchor_kernel(const float* __restrict__ h2,
                                                         float* __restrict__ out) {
    int bb = blockIdx.x / 17;
    int gcol = blockIdx.x % 17;
    int j = threadIdx.x;
    float v = h2[(size_t)bb * OUTD + gcol * 64 + j];
    float mx = wave_max_bcast(v);
    float p = expf(v - mx);
    float sum = wave_sum_bcast(p);
    int ix = j >> 4, iy = (j >> 2) & 3, iz = j & 3;
    float sx = wave_sum_bcast(p * (-1.5f + (float)ix));
    float sy = wave_sum_bcast(p * (-1.5f + (float)iy));
    float sz = wave_sum_bcast(p * (-1.5f + (float)iz));
    if (j == 0) {
        float* o = out + ((size_t)bb * 17 + gcol) * 3;
        o[0] = sx / sum;
        o[1] = sy / sum;
        o[2] = sz / sum;
    }
}

// ---------------------------------------------------------------------------
extern "C" void kernel_launch(void* const* d_in, const int* in_sizes, int n_in,
                              void* d_out, int out_size, void* d_ws, size_t ws_size,
                              hipStream_t stream) {
    const float* points     = (const float*)d_in[0];
    const float* conv_d_w   = (const float*)d_in[1];
    const float* conv_f_w   = (const float*)d_in[2];
    const float* pos_w      = (const float*)d_in[3];
    const float* pos_b      = (const float*)d_in[4];
    const float* ln1_g      = (const float*)d_in[5];
    const float* ln1_b      = (const float*)d_in[6];
    const float* qkv_w      = (const float*)d_in[7];
    const float* attn_out_w = (const float*)d_in[8];
    const float* attn_out_b = (const float*)d_in[9];
    const float* ln2_g      = (const float*)d_in[10];
    const float* ln2_b      = (const float*)d_in[11];
    const float* ff1_w      = (const float*)d_in[12];
    const float* ff1_b      = (const float*)d_in[13];
    const float* ff2_w      = (const float*)d_in[14];
    const float* ff2_b      = (const float*)d_in[15];
    const float* head_ln_g  = (const float*)d_in[16];
    const float* head_ln_b  = (const float*)d_in[17];
    const float* head1_w    = (const float*)d_in[18];
    const float* head1_b    = (const float*)d_in[19];
    const float* head2_w    = (const float*)d_in[20];
    const float* head2_b    = (const float*)d_in[21];

    // fp32 region
    float* ws = (float*)d_ws;
    float* pts    = ws;                    //   499,200 f
    float* axyz   = pts + 499200;          //    18,720 f
    float* xbuf   = axyz + 18720;          // 3,194,880 f
    float* qkvreg = xbuf + 3194880;        // 9,601,024 f (qk + vT, hi/lo)
    float* pooled = qkvreg + 9601024;      //     4,096 f
    float* h1     = pooled + 4096;         //     8,192 f
    float* h2     = h1 + 8192;             //     8,704 f
    float* fend   = h2 + 8704;
    // qk (stride 1024) + vT hi/lo inside qkvreg
    ushort_t* qkh = (ushort_t*)qkvreg;             // 6,389,760 us
    ushort_t* qkl = qkh + 6389760;                 // 6,389,760 us
    ushort_t* vth = qkl + 6389760;                 // 3,211,264 us (8*8*64*784)
    ushort_t* vtl = vth + 3211264;                 // 3,211,264 us
    // bf16 hi/lo region (ushort)
    ushort_t* us   = (ushort_t*)fend;
    ushort_t* xnh  = us;                   // 3,194,880 us
    ushort_t* xnl  = xnh + 3194880;
    ushort_t* atth = xnl + 3194880;
    ushort_t* attl = atth + 3194880;
    ushort_t* ffhh = attl + 3194880;       // 6,389,760 us
    ushort_t* ffhl = ffhh + 6389760;
    ushort_t* wbh  = ffhl + 6389760;       // 2 x WBUFSZ (ping-pong weights, hi)
    ushort_t* wbl  = wbh + 2 * WBUFSZ;     // 2 x WBUFSZ (lo)
    float* ppart = qkvreg;                 // alias: qkv dead after last layer

    build_pts_kernel<<<650, 256, 0, stream>>>(points, pts);
    // fps + layer-0 wsplit fused (blocks 24..2071 do wsplit into buffer 0)
    fps_ws_kernel<<<24 + 2048, 1024, 0, stream>>>(
        pts, axyz, qkv_w, attn_out_w, ff1_w, ff2_w, wbh, wbl);
    group_conv_kernel<<<NROWS, 64, 0, stream>>>(pts, axyz, conv_d_w, conv_f_w,
                                                pos_w, pos_b, xbuf);
    const int MB = (NROWS + 127) / 128;    // 49 row-blocks
    for (int l = 0; l < 5; l++) {
        ushort_t* wth = wbh + (size_t)(l & 1) * WBUFSZ;
        ushort_t* wtl = wbl + (size_t)(l & 1) * WBUFSZ;
        ushort_t* nth = wbh + (size_t)((l + 1) & 1) * WBUFSZ;
        ushort_t* ntl = wbl + (size_t)((l + 1) & 1) * WBUFSZ;
        int ln2off = l * 512;
        ln_kernel<<<NROWS, 64, 0, stream>>>(xbuf, ln1_g + ln2off, ln1_b + ln2off, xnh, xnl);
        gemm_mfma<128, 5><<<dim3(1536 / 128, MB), 256, 0, stream>>>(
            xnh, xnl, wth, wtl, nullptr, nullptr, nullptr, qkh, qkl, vth, vtl,
            NROWS, 1536, 512);
        // attn + next-layer wsplit fused (x >= 13 blocks fill buffer (l+1)&1)
        int lnx = l + 1;
        attn_mfma_kernel<<<dim3(l < 4 ? 45 : 13, NHEAD, BB), 256, 0, stream>>>(
            qkh, qkl, vth, vtl, atth, attl,
            l < 4 ? qkv_w + (size_t)lnx * 512 * 1536 : nullptr,
            l < 4 ? attn_out_w + (size_t)lnx * 512 * 512 : nullptr,
            l < 4 ? ff1_w + (size_t)lnx * 512 * 1024 : nullptr,
            l < 4 ? ff2_w + (size_t)lnx * 1024 * 512 : nullptr,
            nth, ntl);
        gemm_mfma<64, 3><<<dim3(512 / 64, MB), 256, 0, stream>>>(
            atth, attl, wth + 786432, wtl + 786432, attn_out_b + ln2off, xbuf,
            xbuf, nullptr, nullptr, nullptr, nullptr, NROWS, 512, 512);
        ln_kernel<<<NROWS, 64, 0, stream>>>(xbuf, ln2_g + ln2off, ln2_b + ln2off, xnh, xnl);
        gemm_mfma<128, 2><<<dim3(1024 / 128, MB), 256, 0, stream>>>(
            xnh, xnl, wth + 1048576, wtl + 1048576, ff1_b + l * 1024, nullptr,
            nullptr, ffhh, ffhl, nullptr, nullptr, NROWS, 1024, 512);
        gemm_mfma<64, 3><<<dim3(512 / 64, MB), 256, 0, stream>>>(
            ffhh, ffhl, wth + 1572864, wtl + 1572864, ff2_b + ln2off, xbuf,
            xbuf, nullptr, nullptr, nullptr, nullptr, NROWS, 512, 1024);
    }
    pool_max_kernel<<<dim3(13, BB), 512, 0, stream>>>(xbuf, ppart);
    pool_ln_kernel<<<BB, 512, 0, stream>>>(ppart, head_ln_g, head_ln_b, pooled);
    head1_kernel<<<dim3(16, BB), 256, 0, stream>>>(pooled, head1_w, head1_b, h1);
    head2_kernel<<<dim3(17, BB), 256, 0, stream>>>(h1, head2_w, head2_b, h2);
    smax_anchor_kernel<<<BB * 17, 64, 0, stream>>>(h2, (float*)d_out);
}